// Round 9
// baseline (12001.388 us; speedup 1.0000x reference)
//
#include <hip/hip_runtime.h>

typedef unsigned short u16;
typedef unsigned u32;
typedef unsigned long long u64;
typedef __bf16 bf16x8 __attribute__((ext_vector_type(8)));
typedef u16 u16x8 __attribute__((ext_vector_type(8)));
typedef u16 u16x4 __attribute__((ext_vector_type(4)));
typedef float f32x4 __attribute__((ext_vector_type(4)));

__device__ __forceinline__ u16 f2bf(float f){
    unsigned u = __builtin_bit_cast(unsigned, f);
    u = (u + 0x7fffu + ((u >> 16) & 1u)) >> 16;
    return (u16)u;
}
__device__ __forceinline__ float bf2f(u16 h){
    unsigned u = ((unsigned)h) << 16;
    return __builtin_bit_cast(float, u);
}
__device__ __forceinline__ float sigmoidf_(float x){ return 1.0f / (1.0f + __expf(-x)); }
__device__ __forceinline__ float tanhf_(float x){
    float e = __expf(2.0f * x);
    return 1.0f - 2.0f / (e + 1.0f);
}

#define AL(p)   __hip_atomic_load((p), __ATOMIC_RELAXED, __HIP_MEMORY_SCOPE_AGENT)
#define AS(p,v) __hip_atomic_store((p),(v), __ATOMIC_RELAXED, __HIP_MEMORY_SCOPE_AGENT)
#define AA(p,v) __hip_atomic_fetch_add((p),(v), __ATOMIC_RELAXED, __HIP_MEMORY_SCOPE_AGENT)

// ---------------------------------------------------------------------------
// Kernel 0: pack Wx^T / Wh^T gate-interleaved bf16 (pk = 4*hcol + gate),
// bias (bx+bh), zero ring counters (segcnt[1024] + recprog[16]).
// ---------------------------------------------------------------------------
__global__ __launch_bounds__(256) void lstm_pack(
    const float* __restrict__ Wgx, const float* __restrict__ Wix,
    const float* __restrict__ Wfx, const float* __restrict__ Wox,
    const float* __restrict__ Wgh, const float* __restrict__ Wih,
    const float* __restrict__ Wfh, const float* __restrict__ Woh,
    const float* __restrict__ bgx, const float* __restrict__ bgh,
    const float* __restrict__ bix, const float* __restrict__ bih,
    const float* __restrict__ bfx, const float* __restrict__ bfh,
    const float* __restrict__ box, const float* __restrict__ boh,
    u16* __restrict__ Wxpt, u16* __restrict__ Whpt,
    float* __restrict__ biasp, u32* __restrict__ flags)
{
    int idx = blockIdx.x * 256 + threadIdx.x;   // 512 blocks -> 131072 threads
    if (idx < 1040) AS(flags + idx, 0u);
    const float* Wx4[4] = {Wgx, Wix, Wfx, Wox};
    const float* Wh4[4] = {Wgh, Wih, Wfh, Woh};
    if (idx < 131072){
        int pk = idx >> 7, k = idx & 127;
        Wxpt[idx] = f2bf(Wx4[pk & 3][k * 256 + (pk >> 2)]);
    }
    for (int o = idx; o < 262144; o += 131072){
        int pk = o >> 8, k = o & 255;
        Whpt[o] = f2bf(Wh4[pk & 3][k * 256 + (pk >> 2)]);
    }
    if (idx < 1024){
        const float* bx4[4] = {bgx, bix, bfx, box};
        const float* bh4[4] = {bgh, bih, bfh, boh};
        biasp[idx] = bx4[idx & 3][idx >> 2] + bh4[idx & 3][idx >> 2];
    }
}

// ---------------------------------------------------------------------------
// Kernel 1: fused producer/consumer, 80 blocks x 1024 threads (16 waves).
//  blocks 0..15 : REC — block g owns rows [16g,16g+16) and ALL 1024 pk.
//    Wave w owns pk [64w,64w+64): Wh^T slice = 32 frags = 128 VGPRs, ALL in
//    registers (launch_bounds(1024,4) -> up to 512 VGPR/wave, no spill).
//    h in 8KB LDS, XOR-swizzled 16B groups (cg^row) -> <=2-way conflicts.
//    xq prefetched one step ahead AFTER barrier B1 (hidden under MFMA).
//  blocks 16..79: PRODUCERS — block covers rows [16(p&15),..+16) and pk
//    [256(p>>4),..+256); fills IC ring seg-by-seg, throttled by rec progress.
// Cross-block traffic: relaxed agent atomics via IC (proven R2/R8).
// ---------------------------------------------------------------------------
__global__ __launch_bounds__(1024, 4) void lstm_fused(
    const float* __restrict__ x,
    const u16* __restrict__ Wxpt, const u16* __restrict__ Whpt,
    const float* __restrict__ biasp,
    u16* __restrict__ ring, u32* __restrict__ segcnt, u32* __restrict__ recprog,
    float* __restrict__ hT, int seg, int nseg)
{
    __shared__ char lds[65536];
    const int tid = threadIdx.x;
    const int w = tid >> 6, l = tid & 63;
    const int l15 = l & 15, l4 = l >> 4;
    const int bid = blockIdx.x;

    if (bid < 16){
        // ========================= REC =========================
        const int g = bid;
        char* HLDS = lds;                   // [16 rows][512B], XOR-swizzled

        // Wh^T fragments: all 32 in VGPRs (frag f = i*8+kf)
        bf16x8 wv[32];
        #pragma unroll
        for (int i = 0; i < 4; ++i)
            #pragma unroll
            for (int kf = 0; kf < 8; ++kf){
                int pkA = (w << 6) + (i << 4) + l15;
                wv[i * 8 + kf] = __builtin_bit_cast(bf16x8,
                    *(const u16x8*)(Whpt + (size_t)pkA * 256 + kf * 32 + l4 * 8));
            }
        float c[4] = {0.f, 0.f, 0.f, 0.f};
        u64 xc[4], xn[4];
        bool gaveup = false;

        for (int s = 0; s < nseg; ++s){
            if (tid == 0 && !gaveup){               // 1 poll / segment
                u64 wd = __builtin_amdgcn_s_memrealtime();
                while (AL(segcnt + s) < 64u){
                    if (__builtin_amdgcn_s_memrealtime() - wd > 50000000ull){
                        gaveup = true; break;
                    }
                    __builtin_amdgcn_s_sleep(8);
                }
            }
            __syncthreads();                        // uniform proceed
            const u16* rseg = ring + (size_t)((s & 1) * seg) * 262144
                            + (size_t)(g * 16 + l15) * 1024 + (w << 6) + (l4 << 2);
            #pragma unroll
            for (int i = 0; i < 4; ++i)             // xq for tl=0 (exposed 1x/seg)
                xc[i] = AL((const u64*)(rseg + (i << 4)));

            for (int tl = 0; tl < seg; ++tl){
                int t = s * seg + tl;
                bf16x8 hf[8];
                if (t > 0){
                    #pragma unroll
                    for (int kf = 0; kf < 8; ++kf)
                        hf[kf] = __builtin_bit_cast(bf16x8,
                            *(const u16x8*)(HLDS + l15 * 512
                                            + ((((kf << 2) + l4) ^ l15) << 4)));
                }
                __syncthreads();                    // B1: h[t-1] reads done
                if (tl + 1 < seg){                  // prefetch next xq (hidden)
                    const u16* rn = rseg + (size_t)(tl + 1) * 262144;
                    #pragma unroll
                    for (int i = 0; i < 4; ++i)
                        xn[i] = AL((const u64*)(rn + (i << 4)));
                }
                #pragma unroll
                for (int i = 0; i < 4; ++i){
                    f32x4 acc = {0.f, 0.f, 0.f, 0.f};
                    if (t > 0){
                        #pragma unroll
                        for (int kf = 0; kf < 8; ++kf)
                            acc = __builtin_amdgcn_mfma_f32_16x16x32_bf16(
                                      wv[i * 8 + kf], hf[kf], acc, 0, 0, 0);
                    }
                    u16x4 x4 = __builtin_bit_cast(u16x4, xc[i]);
                    float gv = tanhf_(bf2f(x4[0]) + acc[0]);
                    float iv = sigmoidf_(bf2f(x4[1]) + acc[1]);
                    float fv = sigmoidf_(bf2f(x4[2]) + acc[2]);
                    float ov = sigmoidf_(bf2f(x4[3]) + acc[3]);
                    c[i] = gv * iv + c[i] * fv;
                    float hv = tanhf_(c[i]) * ov;
                    int hcol = (w << 4) + (i << 2) + l4;
                    *(u16*)(HLDS + l15 * 512 + ((((hcol >> 3) ^ l15)) << 4)
                            + ((hcol & 7) << 1)) = f2bf(hv);
                    if (t == 1023) hT[(size_t)(g * 16 + l15) * 256 + hcol] = hv;
                }
                __syncthreads();                    // B2: h[t] writes visible
                #pragma unroll
                for (int i = 0; i < 4; ++i) xc[i] = xn[i];
            }
            if (tid == 0) AS(recprog + g, (u32)(s + 1));
        }
        if (gaveup && tid == 0)                     // decisive poison
            for (int j = 0; j < 256; ++j) hT[(size_t)(g * 16) * 256 + j] = 1e30f;
    } else {
        // ====================== PRODUCER =======================
        const int p = bid - 16;                     // 0..63
        const int pr = p & 15, pc = p >> 4;
        const int n0 = pc << 8;                     // 256-pk slice base
        u16* Bt = (u16*)lds;                        // 64KB Wx tile, swizzled
        for (int ii = 0; ii < 4; ++ii){
            int cid = ii * 1024 + tid;              // 4096 x 16B chunks
            int nn = cid >> 4, kc = (cid & 15) << 3;
            u16x8 v = *(const u16x8*)(Wxpt + (size_t)(n0 + nn) * 128 + kc);
            u32 byte = ((u32)(nn << 8) + (u32)(kc << 1)) ^ ((u32)(nn & 7) << 4);
            *(u16x8*)((char*)Bt + byte) = v;
        }
        __syncthreads();
        const int b = pr * 16 + l15;                // batch row
        const int pkg = n0 + (w << 4) + (l4 << 2);  // lane's 4 pk
        const f32x4 bias4 = *(const f32x4*)(biasp + pkg);
        const float* xr = x + (size_t)b * 1024 * 128;
        const int nnA = (w << 4) + l15;
        bool gaveup = false;

        for (int s = 0; s < nseg; ++s){
            if (s >= 2 && tid == 0 && !gaveup){     // ring-reuse throttle
                u64 wd = __builtin_amdgcn_s_memrealtime();
                for (;;){
                    u32 mn = 0xffffffffu;
                    for (int j = 0; j < 16; ++j){
                        u32 v = AL(recprog + j);
                        mn = v < mn ? v : mn;
                    }
                    if ((int)mn >= s - 1) break;
                    if (__builtin_amdgcn_s_memrealtime() - wd > 50000000ull){
                        gaveup = true; break;
                    }
                    __builtin_amdgcn_s_sleep(32);
                }
            }
            __syncthreads();                        // uniform proceed

            for (int tl = 0; tl < seg; ++tl){
                int t = s * seg + tl;
                f32x4 acc = {0.f, 0.f, 0.f, 0.f};
                #pragma unroll
                for (int kf = 0; kf < 4; ++kf){
                    int k0 = kf * 32 + l4 * 8;
                    f32x4 xa = *(const f32x4*)(xr + (size_t)t * 128 + k0);
                    f32x4 xb = *(const f32x4*)(xr + (size_t)t * 128 + k0 + 4);
                    u16x8 bu;
                    bu[0]=f2bf(xa[0]); bu[1]=f2bf(xa[1]); bu[2]=f2bf(xa[2]); bu[3]=f2bf(xa[3]);
                    bu[4]=f2bf(xb[0]); bu[5]=f2bf(xb[1]); bu[6]=f2bf(xb[2]); bu[7]=f2bf(xb[3]);
                    u32 byte = ((u32)(nnA << 8) + (u32)(k0 << 1)) ^ ((u32)(nnA & 7) << 4);
                    bf16x8 af = __builtin_bit_cast(bf16x8,
                                    *(const u16x8*)((const char*)Bt + byte));
                    acc = __builtin_amdgcn_mfma_f32_16x16x32_bf16(
                              af, __builtin_bit_cast(bf16x8, bu), acc, 0, 0, 0);
                }
                acc += bias4;                       // fold bias into xg
                u16x4 o;
                o[0]=f2bf(acc[0]); o[1]=f2bf(acc[1]); o[2]=f2bf(acc[2]); o[3]=f2bf(acc[3]);
                size_t ridx = ((size_t)((s & 1) * seg + tl)) * 262144
                            + (size_t)b * 1024 + pkg;
                AS((u64*)(ring + ridx), __builtin_bit_cast(u64, o));
            }
            __syncthreads();                        // vmcnt(0): stores at IC
            if (tid == 0) AA(segcnt + s, 1u);       // publish segment
        }
    }
}

// ---------------------------------------------------------------------------
// Kernel 2: p = hT @ Wph + bph; softmax over 10.
// ---------------------------------------------------------------------------
__global__ __launch_bounds__(256) void lstm_head(
    const float* __restrict__ hT, const float* __restrict__ Wph,
    const float* __restrict__ bph, float* __restrict__ out)
{
    int b = threadIdx.x;
    float p[10];
    #pragma unroll
    for (int j = 0; j < 10; ++j) p[j] = bph[j];
    const float* hr = hT + (size_t)b * 256;
    for (int k = 0; k < 256; ++k){
        float h = hr[k];
        const float* wr = Wph + k * 10;
        #pragma unroll
        for (int j = 0; j < 10; ++j) p[j] += h * wr[j];
    }
    float m = p[0];
    #pragma unroll
    for (int j = 1; j < 10; ++j) m = fmaxf(m, p[j]);
    float s = 0.f;
    #pragma unroll
    for (int j = 0; j < 10; ++j){ p[j] = __expf(p[j] - m); s += p[j]; }
    float inv = 1.f / s;
    #pragma unroll
    for (int j = 0; j < 10; ++j) out[b * 10 + j] = p[j] * inv;
}

// ---------------------------------------------------------------------------
extern "C" void kernel_launch(void* const* d_in, const int* in_sizes, int n_in,
                              void* d_out, int out_size, void* d_ws, size_t ws_size,
                              hipStream_t stream)
{
    const float* x   = (const float*)d_in[0];
    const float* Wgx = (const float*)d_in[1];  const float* bgx = (const float*)d_in[2];
    const float* Wgh = (const float*)d_in[3];  const float* bgh = (const float*)d_in[4];
    const float* Wix = (const float*)d_in[5];  const float* bix = (const float*)d_in[6];
    const float* Wih = (const float*)d_in[7];  const float* bih = (const float*)d_in[8];
    const float* Wfx = (const float*)d_in[9];  const float* bfx = (const float*)d_in[10];
    const float* Wfh = (const float*)d_in[11]; const float* bfh = (const float*)d_in[12];
    const float* Wox = (const float*)d_in[13]; const float* box = (const float*)d_in[14];
    const float* Woh = (const float*)d_in[15]; const float* boh = (const float*)d_in[16];
    const float* Wph = (const float*)d_in[17]; const float* bph = (const float*)d_in[18];
    float* out = (float*)d_out;

    char* ws = (char*)d_ws;
    u32*   flags = (u32*)  (ws + 0);         // segcnt[1024] + recprog[16]
    float* hT    = (float*)(ws + 8192);      // 256KB -> 270336
    u16*   Whpt  = (u16*)  (ws + 270336);    // 512KB -> 794624
    u16*   Wxpt  = (u16*)  (ws + 794624);    // 256KB -> 1056768
    float* biasp = (float*)(ws + 1056768);   // 4KB   -> 1060864
    u16*   ring  = (u16*)  (ws + 1060864);   // 2 x seg x 512KB

    size_t avail = ws_size > 1060864 ? ws_size - 1060864 : 0;
    int seg = 8;
    while (seg > 1 && (size_t)seg * 1048576 > avail) seg >>= 1;
    int nseg = 1024 / seg;

    lstm_pack<<<dim3(512), dim3(256), 0, stream>>>(
        Wgx, Wix, Wfx, Wox, Wgh, Wih, Wfh, Woh,
        bgx, bgh, bix, bih, bfx, bfh, box, boh,
        Wxpt, Whpt, biasp, flags);
    lstm_fused<<<dim3(80), dim3(1024), 0, stream>>>(
        x, Wxpt, Whpt, biasp, ring, flags, flags + 1024, hT, seg, nseg);
    lstm_head<<<dim3(1), dim3(256), 0, stream>>>(hT, Wph, bph, out);
}

// Round 10
// 7152.997 us; speedup vs baseline: 1.6778x; 1.6778x over previous
//
#include <hip/hip_runtime.h>

typedef unsigned short u16;
typedef unsigned u32;
typedef unsigned long long u64;
typedef __bf16 bf16x8 __attribute__((ext_vector_type(8)));
typedef u16 u16x8 __attribute__((ext_vector_type(8)));
typedef u16 u16x4 __attribute__((ext_vector_type(4)));
typedef float f32x4 __attribute__((ext_vector_type(4)));

__device__ __forceinline__ u16 f2bf(float f){
    unsigned u = __builtin_bit_cast(unsigned, f);
    u = (u + 0x7fffu + ((u >> 16) & 1u)) >> 16;
    return (u16)u;
}
__device__ __forceinline__ float bf2f(u16 h){
    unsigned u = ((unsigned)h) << 16;
    return __builtin_bit_cast(float, u);
}
__device__ __forceinline__ float sigmoidf_(float x){ return 1.0f / (1.0f + __expf(-x)); }
__device__ __forceinline__ float tanhf_(float x){
    float e = __expf(2.0f * x);
    return 1.0f - 2.0f / (e + 1.0f);
}

#define AL(p)   __hip_atomic_load((p), __ATOMIC_RELAXED, __HIP_MEMORY_SCOPE_AGENT)
#define AS(p,v) __hip_atomic_store((p),(v), __ATOMIC_RELAXED, __HIP_MEMORY_SCOPE_AGENT)
#define AA(p,v) __hip_atomic_fetch_add((p),(v), __ATOMIC_RELAXED, __HIP_MEMORY_SCOPE_AGENT)

// ---------------------------------------------------------------------------
// Kernel 0: pack Wx^T / Wh^T gate-interleaved bf16 (pk = 4*hcol + gate),
// bias (bx+bh), zero ring counters (segcnt[1024] + recprog[16]).
// ---------------------------------------------------------------------------
__global__ __launch_bounds__(256) void lstm_pack(
    const float* __restrict__ Wgx, const float* __restrict__ Wix,
    const float* __restrict__ Wfx, const float* __restrict__ Wox,
    const float* __restrict__ Wgh, const float* __restrict__ Wih,
    const float* __restrict__ Wfh, const float* __restrict__ Woh,
    const float* __restrict__ bgx, const float* __restrict__ bgh,
    const float* __restrict__ bix, const float* __restrict__ bih,
    const float* __restrict__ bfx, const float* __restrict__ bfh,
    const float* __restrict__ box, const float* __restrict__ boh,
    u16* __restrict__ Wxpt, u16* __restrict__ Whpt,
    float* __restrict__ biasp, u32* __restrict__ flags)
{
    int idx = blockIdx.x * 256 + threadIdx.x;   // 512 blocks -> 131072 threads
    if (idx < 1040) AS(flags + idx, 0u);
    const float* Wx4[4] = {Wgx, Wix, Wfx, Wox};
    const float* Wh4[4] = {Wgh, Wih, Wfh, Woh};
    if (idx < 131072){
        int pk = idx >> 7, k = idx & 127;
        Wxpt[idx] = f2bf(Wx4[pk & 3][k * 256 + (pk >> 2)]);
    }
    for (int o = idx; o < 262144; o += 131072){
        int pk = o >> 8, k = o & 255;
        Whpt[o] = f2bf(Wh4[pk & 3][k * 256 + (pk >> 2)]);
    }
    if (idx < 1024){
        const float* bx4[4] = {bgx, bix, bfx, box};
        const float* bh4[4] = {bgh, bih, bfh, boh};
        biasp[idx] = bx4[idx & 3][idx >> 2] + bh4[idx & 3][idx >> 2];
    }
}

// ---------------------------------------------------------------------------
// Kernel 1: fused producer/consumer, 144 blocks x 512 threads, 152KB LDS
// (=> 1 block/CU, all co-resident). amdgpu_waves_per_eu(2,2) pins exactly
// 2 waves/SIMD so the allocator gets the FULL 256-VGPR/wave budget — the
// R8/R9 failure was the compiler budgeting for 2 blocks/CU (128/64 VGPRs)
// and spilling the resident Wh fragments to scratch.
//  blocks 0..15 : REC — block g owns rows [16g,16g+16) and ALL 1024 pk.
//    Wave w owns pk [128w,128w+128) = 8 tiles x 8 kf = 64 frags:
//    46 in VGPRs (184 regs) + 18 in LDS (18KB/wave, 144KB). h in 8KB LDS.
//  blocks 16..143: PRODUCERS (R8-proven form) — p covers rows [16(p&15),..)
//    and pk [128(p>>4),..); fills IC ring seg-by-seg, throttled by recprog.
// Cross-block traffic: relaxed agent atomics via IC (proven R2/R8).
// ---------------------------------------------------------------------------
__global__ __launch_bounds__(512)
__attribute__((amdgpu_waves_per_eu(2, 2)))
void lstm_fused(
    const float* __restrict__ x,
    const u16* __restrict__ Wxpt, const u16* __restrict__ Whpt,
    const float* __restrict__ biasp,
    u16* __restrict__ ring, u32* __restrict__ segcnt, u32* __restrict__ recprog,
    float* __restrict__ hT, int seg, int nseg)
{
    __shared__ char lds[155648];        // rec: 8w x 18 frags x 1KB + 8KB h
    const int tid = threadIdx.x;
    const int w = tid >> 6, l = tid & 63;
    const int l15 = l & 15, l4 = l >> 4;
    const int bid = blockIdx.x;

    if (bid < 16){
        // ========================= REC =========================
        const int g = bid;
        char* WLDS = lds;               // [8 waves][18 frags][1KB]
        char* HLDS = lds + 147456;      // [16 rows][512B], XOR-swizzled

        // Wh^T fragments, frag f = i*8+kf (tile i of 8, kf of 8):
        // f < 46 -> VGPR; f >= 46 -> LDS (static split, unrolled).
        bf16x8 wv[46];
        #pragma unroll
        for (int f = 0; f < 46; ++f){
            int i = f >> 3, kf = f & 7;
            wv[f] = __builtin_bit_cast(bf16x8,
                *(const u16x8*)(Whpt + (size_t)((w << 7) + (i << 4) + l15) * 256
                                + kf * 32 + l4 * 8));
        }
        #pragma unroll
        for (int fl = 0; fl < 18; ++fl){
            int f = 46 + fl, i = f >> 3, kf = f & 7;
            u16x8 v = *(const u16x8*)(Whpt + (size_t)((w << 7) + (i << 4) + l15) * 256
                                      + kf * 32 + l4 * 8);
            *(u16x8*)(WLDS + ((w * 18 + fl) << 10) + (l << 4)) = v;
        }
        float c[8] = {0.f, 0.f, 0.f, 0.f, 0.f, 0.f, 0.f, 0.f};
        __syncthreads();

        bool gaveup = false;
        for (int s = 0; s < nseg; ++s){
            if (tid == 0 && !gaveup){               // 1 poll / segment
                u64 wd = __builtin_amdgcn_s_memrealtime();
                while (AL(segcnt + s) < 128u){
                    if (__builtin_amdgcn_s_memrealtime() - wd > 50000000ull){
                        gaveup = true; break;
                    }
                    __builtin_amdgcn_s_sleep(2);
                }
            }
            __syncthreads();                        // uniform proceed
            const u16* rseg = ring + (size_t)((s & 1) * seg) * 262144
                            + (size_t)(g * 16 + l15) * 1024 + (w << 7) + (l4 << 2);

            for (int tl = 0; tl < seg; ++tl){
                int t = s * seg + tl;
                // xq for THIS step: issue first, consumed after MFMA (hidden)
                const u16* rt = rseg + (size_t)tl * 262144;
                u64 xc[8];
                #pragma unroll
                for (int i = 0; i < 8; ++i)
                    xc[i] = AL((const u64*)(rt + (i << 4)));

                bf16x8 hf[8];
                if (t > 0){
                    #pragma unroll
                    for (int kf = 0; kf < 8; ++kf)
                        hf[kf] = __builtin_bit_cast(bf16x8,
                            *(const u16x8*)(HLDS + l15 * 512
                                            + ((((kf << 2) + l4) ^ l15) << 4)));
                }
                __syncthreads();                    // B1: h[t-1] reads done

                #pragma unroll
                for (int i = 0; i < 8; ++i){
                    f32x4 acc = {0.f, 0.f, 0.f, 0.f};
                    if (t > 0){
                        #pragma unroll
                        for (int kf = 0; kf < 8; ++kf){
                            int f = i * 8 + kf;
                            bf16x8 wa;
                            if (f < 46) wa = wv[f];
                            else wa = __builtin_bit_cast(bf16x8,
                                *(const u16x8*)(WLDS + ((w * 18 + (f - 46)) << 10)
                                                + (l << 4)));
                            acc = __builtin_amdgcn_mfma_f32_16x16x32_bf16(
                                      wa, hf[kf], acc, 0, 0, 0);
                        }
                    }
                    u16x4 x4 = __builtin_bit_cast(u16x4, xc[i]);
                    float gv = tanhf_(bf2f(x4[0]) + acc[0]);
                    float iv = sigmoidf_(bf2f(x4[1]) + acc[1]);
                    float fv = sigmoidf_(bf2f(x4[2]) + acc[2]);
                    float ov = sigmoidf_(bf2f(x4[3]) + acc[3]);
                    c[i] = gv * iv + c[i] * fv;
                    float hv = tanhf_(c[i]) * ov;
                    int hcol = (w << 5) + (i << 2) + l4;
                    *(u16*)(HLDS + l15 * 512 + ((((hcol >> 3) ^ l15)) << 4)
                            + ((hcol & 7) << 1)) = f2bf(hv);
                    if (t == 1023) hT[(size_t)(g * 16 + l15) * 256 + hcol] = hv;
                }
                __syncthreads();                    // B2: h[t] writes visible
            }
            if (tid == 0) AS(recprog + g, (u32)(s + 1));
        }
        if (gaveup && tid == 0)                     // decisive poison
            for (int j = 0; j < 256; ++j) hT[(size_t)(g * 16) * 256 + j] = 1e30f;
    } else {
        // ====================== PRODUCER (R8-proven) =======================
        const int p = bid - 16;                     // 0..127
        const int pr = p & 15, pc = p >> 4;
        const int n0 = pc << 7;                     // 128-pk slice base
        u16* Bt = (u16*)lds;                        // 32KB Wx tile, swizzled
        for (int ii = 0; ii < 4; ++ii){
            int cid = ii * 512 + tid;               // 2048 x 16B chunks
            int nn = cid >> 4, kc = (cid & 15) << 3;
            u16x8 v = *(const u16x8*)(Wxpt + (size_t)(n0 + nn) * 128 + kc);
            u32 byte = ((u32)(nn << 8) + (u32)(kc << 1)) ^ ((u32)(nn & 7) << 4);
            *(u16x8*)((char*)Bt + byte) = v;
        }
        __syncthreads();
        const int b = pr * 16 + l15;                // batch row
        const int pkg = n0 + (w << 4) + (l4 << 2);  // lane's 4 pk
        const f32x4 bias4 = *(const f32x4*)(biasp + pkg);
        const float* xr = x + (size_t)b * 1024 * 128;
        const int nnA = (w << 4) + l15;
        bool gaveup = false;

        for (int s = 0; s < nseg; ++s){
            if (s >= 2 && tid == 0 && !gaveup){     // ring-reuse throttle
                u64 wd = __builtin_amdgcn_s_memrealtime();
                for (;;){
                    u32 mn = 0xffffffffu;
                    for (int j = 0; j < 16; ++j){
                        u32 v = AL(recprog + j);
                        mn = v < mn ? v : mn;
                    }
                    if ((int)mn >= s - 1) break;
                    if (__builtin_amdgcn_s_memrealtime() - wd > 50000000ull){
                        gaveup = true; break;
                    }
                    __builtin_amdgcn_s_sleep(32);
                }
            }
            __syncthreads();                        // uniform proceed

            for (int tl = 0; tl < seg; ++tl){
                int t = s * seg + tl;
                f32x4 acc = {0.f, 0.f, 0.f, 0.f};
                #pragma unroll
                for (int kf = 0; kf < 4; ++kf){
                    int k0 = kf * 32 + l4 * 8;
                    f32x4 xa = *(const f32x4*)(xr + (size_t)t * 128 + k0);
                    f32x4 xb = *(const f32x4*)(xr + (size_t)t * 128 + k0 + 4);
                    u16x8 bu;
                    bu[0]=f2bf(xa[0]); bu[1]=f2bf(xa[1]); bu[2]=f2bf(xa[2]); bu[3]=f2bf(xa[3]);
                    bu[4]=f2bf(xb[0]); bu[5]=f2bf(xb[1]); bu[6]=f2bf(xb[2]); bu[7]=f2bf(xb[3]);
                    u32 byte = ((u32)(nnA << 8) + (u32)(k0 << 1)) ^ ((u32)(nnA & 7) << 4);
                    bf16x8 af = __builtin_bit_cast(bf16x8,
                                    *(const u16x8*)((const char*)Bt + byte));
                    acc = __builtin_amdgcn_mfma_f32_16x16x32_bf16(
                              af, __builtin_bit_cast(bf16x8, bu), acc, 0, 0, 0);
                }
                acc += bias4;                       // fold bias into xg
                u16x4 o;
                o[0]=f2bf(acc[0]); o[1]=f2bf(acc[1]); o[2]=f2bf(acc[2]); o[3]=f2bf(acc[3]);
                size_t ridx = ((size_t)((s & 1) * seg + tl)) * 262144
                            + (size_t)b * 1024 + pkg;
                AS((u64*)(ring + ridx), __builtin_bit_cast(u64, o));
            }
            __syncthreads();                        // vmcnt(0): stores at IC
            if (tid == 0) AA(segcnt + s, 1u);       // publish segment
        }
    }
}

// ---------------------------------------------------------------------------
// Kernel 2: p = hT @ Wph + bph; softmax over 10.
// ---------------------------------------------------------------------------
__global__ __launch_bounds__(256) void lstm_head(
    const float* __restrict__ hT, const float* __restrict__ Wph,
    const float* __restrict__ bph, float* __restrict__ out)
{
    int b = threadIdx.x;
    float p[10];
    #pragma unroll
    for (int j = 0; j < 10; ++j) p[j] = bph[j];
    const float* hr = hT + (size_t)b * 256;
    for (int k = 0; k < 256; ++k){
        float h = hr[k];
        const float* wr = Wph + k * 10;
        #pragma unroll
        for (int j = 0; j < 10; ++j) p[j] += h * wr[j];
    }
    float m = p[0];
    #pragma unroll
    for (int j = 1; j < 10; ++j) m = fmaxf(m, p[j]);
    float s = 0.f;
    #pragma unroll
    for (int j = 0; j < 10; ++j){ p[j] = __expf(p[j] - m); s += p[j]; }
    float inv = 1.f / s;
    #pragma unroll
    for (int j = 0; j < 10; ++j) out[b * 10 + j] = p[j] * inv;
}

// ---------------------------------------------------------------------------
extern "C" void kernel_launch(void* const* d_in, const int* in_sizes, int n_in,
                              void* d_out, int out_size, void* d_ws, size_t ws_size,
                              hipStream_t stream)
{
    const float* x   = (const float*)d_in[0];
    const float* Wgx = (const float*)d_in[1];  const float* bgx = (const float*)d_in[2];
    const float* Wgh = (const float*)d_in[3];  const float* bgh = (const float*)d_in[4];
    const float* Wix = (const float*)d_in[5];  const float* bix = (const float*)d_in[6];
    const float* Wih = (const float*)d_in[7];  const float* bih = (const float*)d_in[8];
    const float* Wfx = (const float*)d_in[9];  const float* bfx = (const float*)d_in[10];
    const float* Wfh = (const float*)d_in[11]; const float* bfh = (const float*)d_in[12];
    const float* Wox = (const float*)d_in[13]; const float* box = (const float*)d_in[14];
    const float* Woh = (const float*)d_in[15]; const float* boh = (const float*)d_in[16];
    const float* Wph = (const float*)d_in[17]; const float* bph = (const float*)d_in[18];
    float* out = (float*)d_out;

    char* ws = (char*)d_ws;
    u32*   flags = (u32*)  (ws + 0);         // segcnt[1024] + recprog[16]
    float* hT    = (float*)(ws + 8192);      // 256KB -> 270336
    u16*   Whpt  = (u16*)  (ws + 270336);    // 512KB -> 794624
    u16*   Wxpt  = (u16*)  (ws + 794624);    // 256KB -> 1056768
    float* biasp = (float*)(ws + 1056768);   // 4KB   -> 1060864
    u16*   ring  = (u16*)  (ws + 1060864);   // 2 x seg x 512KB

    size_t avail = ws_size > 1060864 ? ws_size - 1060864 : 0;
    int seg = 8;
    while (seg > 1 && (size_t)seg * 1048576 > avail) seg >>= 1;
    int nseg = 1024 / seg;

    lstm_pack<<<dim3(512), dim3(256), 0, stream>>>(
        Wgx, Wix, Wfx, Wox, Wgh, Wih, Wfh, Woh,
        bgx, bgh, bix, bih, bfx, bfh, box, boh,
        Wxpt, Whpt, biasp, flags);
    lstm_fused<<<dim3(144), dim3(512), 0, stream>>>(
        x, Wxpt, Whpt, biasp, ring, flags, flags + 1024, hT, seg, nseg);
    lstm_head<<<dim3(1), dim3(256), 0, stream>>>(hT, Wph, bph, out);
}

// Round 11
// 7037.000 us; speedup vs baseline: 1.7055x; 1.0165x over previous
//
#include <hip/hip_runtime.h>

typedef unsigned short u16;
typedef unsigned u32;
typedef unsigned long long u64;
typedef __bf16 bf16x8 __attribute__((ext_vector_type(8)));
typedef u16 u16x8 __attribute__((ext_vector_type(8)));
typedef u16 u16x4 __attribute__((ext_vector_type(4)));
typedef float f32x4 __attribute__((ext_vector_type(4)));

__device__ __forceinline__ u16 f2bf(float f){
    unsigned u = __builtin_bit_cast(unsigned, f);
    u = (u + 0x7fffu + ((u >> 16) & 1u)) >> 16;
    return (u16)u;
}
__device__ __forceinline__ float bf2f(u16 h){
    unsigned u = ((unsigned)h) << 16;
    return __builtin_bit_cast(float, u);
}
__device__ __forceinline__ float sigmoidf_(float x){ return 1.0f / (1.0f + __expf(-x)); }
__device__ __forceinline__ float tanhf_(float x){
    float e = __expf(2.0f * x);
    return 1.0f - 2.0f / (e + 1.0f);
}

#define AL(p)   __hip_atomic_load((p), __ATOMIC_RELAXED, __HIP_MEMORY_SCOPE_AGENT)
#define AS(p,v) __hip_atomic_store((p),(v), __ATOMIC_RELAXED, __HIP_MEMORY_SCOPE_AGENT)
#define AA(p,v) __hip_atomic_fetch_add((p),(v), __ATOMIC_RELAXED, __HIP_MEMORY_SCOPE_AGENT)

// ---------------------------------------------------------------------------
// Kernel 0: pack Wx^T / Wh^T gate-interleaved bf16 (pk = 4*hcol + gate),
// bias (bx+bh), zero counters (segcnt[1024] @flags[0..], recdone @flags[1032]).
// ---------------------------------------------------------------------------
__global__ __launch_bounds__(256) void lstm_pack(
    const float* __restrict__ Wgx, const float* __restrict__ Wix,
    const float* __restrict__ Wfx, const float* __restrict__ Wox,
    const float* __restrict__ Wgh, const float* __restrict__ Wih,
    const float* __restrict__ Wfh, const float* __restrict__ Woh,
    const float* __restrict__ bgx, const float* __restrict__ bgh,
    const float* __restrict__ bix, const float* __restrict__ bih,
    const float* __restrict__ bfx, const float* __restrict__ bfh,
    const float* __restrict__ box, const float* __restrict__ boh,
    u16* __restrict__ Wxpt, u16* __restrict__ Whpt,
    float* __restrict__ biasp, u32* __restrict__ flags)
{
    int idx = blockIdx.x * 256 + threadIdx.x;   // 512 blocks -> 131072 threads
    if (idx < 1040) AS(flags + idx, 0u);
    const float* Wx4[4] = {Wgx, Wix, Wfx, Wox};
    const float* Wh4[4] = {Wgh, Wih, Wfh, Woh};
    if (idx < 131072){
        int pk = idx >> 7, k = idx & 127;
        Wxpt[idx] = f2bf(Wx4[pk & 3][k * 256 + (pk >> 2)]);
    }
    for (int o = idx; o < 262144; o += 131072){
        int pk = o >> 8, k = o & 255;
        Whpt[o] = f2bf(Wh4[pk & 3][k * 256 + (pk >> 2)]);
    }
    if (idx < 1024){
        const float* bx4[4] = {bgx, bix, bfx, box};
        const float* bh4[4] = {bgh, bih, bfh, boh};
        biasp[idx] = bx4[idx & 3][idx >> 2] + bh4[idx & 3][idx >> 2];
    }
}

// ---------------------------------------------------------------------------
// Kernel 1: fused producer/consumer, 144 blocks x 512 thr, 152KB LDS
// (1 block/CU, all co-resident — R8/R10-proven envelope).
//  blocks 0..15 : REC — block g owns rows [16g,16g+16), ALL 1024 pk.
//    W residency enforced: 46 frags/wave through asm-opaque values (cannot
//    be rematerialized; spill target is AGPR not memory) + 18 frags/wave LDS.
//    Step loop uses RAW s_barrier + lgkmcnt(0) only — no vmcnt drain, so the
//    IC xg loads hide under MFMA. h in 8KB LDS (XOR-swizzled, R10-proven).
//  blocks 16..143: PRODUCERS (R10 form) writing a 3-DEEP ring: depth 3 lets
//    producers run a full segment ahead (depth 2 forced a serial handoff).
//    Throttle: segment s needs recdone >= 16*(s-2) (rec finished s-3).
// ---------------------------------------------------------------------------
__global__ __launch_bounds__(512, 2) void lstm_fused(
    const float* __restrict__ x,
    const u16* __restrict__ Wxpt, const u16* __restrict__ Whpt,
    const float* __restrict__ biasp,
    u16* __restrict__ ring, u32* __restrict__ segcnt, u32* __restrict__ recdone,
    float* __restrict__ hT, int seg, int nseg)
{
    __shared__ char lds[155648];
    const int tid = threadIdx.x;
    const int w = tid >> 6, l = tid & 63;
    const int l15 = l & 15, l4 = l >> 4;
    const int bid = blockIdx.x;

    if (bid < 16){
        // ========================= REC =========================
        const int g = bid;
        char* WLDS = lds;               // [8 waves][18 frags][1KB]
        char* HLDS = lds + 147456;      // [16 rows][512B], XOR-swizzled

        // Wh^T fragments, frag f = i*8+kf: f<46 -> reg (asm-opaque), else LDS
        bf16x8 wv[46];
        #pragma unroll
        for (int f = 0; f < 46; ++f){
            int i = f >> 3, kf = f & 7;
            wv[f] = __builtin_bit_cast(bf16x8,
                *(const u16x8*)(Whpt + (size_t)((w << 7) + (i << 4) + l15) * 256
                                + kf * 32 + l4 * 8));
        }
        #pragma unroll
        for (int f = 0; f < 46; ++f){   // anti-remat: value becomes asm-defined
            f32x4 tpin = __builtin_bit_cast(f32x4, wv[f]);
            asm volatile("" : "+v"(tpin));
            wv[f] = __builtin_bit_cast(bf16x8, tpin);
        }
        #pragma unroll
        for (int fl = 0; fl < 18; ++fl){
            int f = 46 + fl, i = f >> 3, kf = f & 7;
            u16x8 v = *(const u16x8*)(Whpt + (size_t)((w << 7) + (i << 4) + l15) * 256
                                      + kf * 32 + l4 * 8);
            *(u16x8*)(WLDS + ((w * 18 + fl) << 10) + (l << 4)) = v;
        }
        float c[8] = {0.f, 0.f, 0.f, 0.f, 0.f, 0.f, 0.f, 0.f};
        __syncthreads();

        bool gaveup = false;
        for (int s = 0; s < nseg; ++s){
            if (tid == 0 && !gaveup){               // 1 poll / segment
                u64 wd = __builtin_amdgcn_s_memrealtime();
                while (AL(segcnt + s) < 128u){
                    if (__builtin_amdgcn_s_memrealtime() - wd > 5000000ull){
                        gaveup = true; break;
                    }
                    __builtin_amdgcn_s_sleep(2);
                }
            }
            __syncthreads();                        // (1x/segment, drain ok)
            const u16* rseg = ring + (size_t)(s % 3) * seg * 262144
                            + (size_t)(g * 16 + l15) * 1024 + (w << 7) + (l4 << 2);

            for (int tl = 0; tl < seg; ++tl){
                int t = s * seg + tl;
                const u16* rt = rseg + (size_t)tl * 262144;
                u64 xq[8];
                #pragma unroll
                for (int i = 0; i < 8; ++i)         // IC loads, span barriers
                    xq[i] = AL((const u64*)(rt + (i << 4)));

                float hvs[8];
                if (t > 0){
                    #pragma unroll
                    for (int g2 = 0; g2 < 2; ++g2){
                        f32x4 acc[4];
                        #pragma unroll
                        for (int i2 = 0; i2 < 4; ++i2)
                            acc[i2] = (f32x4){0.f, 0.f, 0.f, 0.f};
                        #pragma unroll
                        for (int kf = 0; kf < 8; ++kf){
                            bf16x8 hb = __builtin_bit_cast(bf16x8,
                                *(const u16x8*)(HLDS + l15 * 512
                                    + ((((kf << 2) + l4) ^ l15) << 4)));
                            #pragma unroll
                            for (int i2 = 0; i2 < 4; ++i2){
                                int f = (g2 * 4 + i2) * 8 + kf;
                                bf16x8 wa;
                                if (f < 46) wa = wv[f];
                                else wa = __builtin_bit_cast(bf16x8,
                                    *(const u16x8*)(WLDS + ((w * 18 + (f - 46)) << 10)
                                                    + (l << 4)));
                                acc[i2] = __builtin_amdgcn_mfma_f32_16x16x32_bf16(
                                              wa, hb, acc[i2], 0, 0, 0);
                            }
                        }
                        #pragma unroll
                        for (int i2 = 0; i2 < 4; ++i2){
                            int i = g2 * 4 + i2;
                            u16x4 x4 = __builtin_bit_cast(u16x4, xq[i]);
                            float gv = tanhf_(bf2f(x4[0]) + acc[i2][0]);
                            float iv = sigmoidf_(bf2f(x4[1]) + acc[i2][1]);
                            float fv = sigmoidf_(bf2f(x4[2]) + acc[i2][2]);
                            float ov = sigmoidf_(bf2f(x4[3]) + acc[i2][3]);
                            c[i] = gv * iv + c[i] * fv;
                            hvs[i] = tanhf_(c[i]) * ov;
                        }
                    }
                } else {
                    #pragma unroll
                    for (int i = 0; i < 8; ++i){
                        u16x4 x4 = __builtin_bit_cast(u16x4, xq[i]);
                        float gv = tanhf_(bf2f(x4[0]));
                        float iv = sigmoidf_(bf2f(x4[1]));
                        float fv = sigmoidf_(bf2f(x4[2]));
                        float ov = sigmoidf_(bf2f(x4[3]));
                        c[i] = gv * iv + c[i] * fv;
                        hvs[i] = tanhf_(c[i]) * ov;
                    }
                }
                // B1: every wave consumed its h reads before arriving
                asm volatile("s_waitcnt lgkmcnt(0)" ::: "memory");
                __builtin_amdgcn_s_barrier();
                #pragma unroll
                for (int i = 0; i < 8; ++i){
                    int hcol = (w << 5) + (i << 2) + l4;
                    *(u16*)(HLDS + l15 * 512 + ((((hcol >> 3) ^ l15)) << 4)
                            + ((hcol & 7) << 1)) = f2bf(hvs[i]);
                    if (t == 1023)
                        hT[(size_t)(g * 16 + l15) * 256 + hcol] = hvs[i];
                }
                // B2: h[t] visible for t+1 reads
                asm volatile("s_waitcnt lgkmcnt(0)" ::: "memory");
                __builtin_amdgcn_s_barrier();
            }
            if (tid == 0) AA(recdone, 1u);
        }
        if (gaveup && tid == 0)                     // decisive poison
            for (int j = 0; j < 256; ++j) hT[(size_t)(g * 16) * 256 + j] = 1e30f;
    } else {
        // ====================== PRODUCER (R10 form, ring-3) ======================
        const int p = bid - 16;                     // 0..127
        const int pr = p & 15, pc = p >> 4;
        const int n0 = pc << 7;                     // 128-pk slice base
        u16* Bt = (u16*)lds;                        // 32KB Wx tile, swizzled
        for (int ii = 0; ii < 4; ++ii){
            int cid = ii * 512 + tid;
            int nn = cid >> 4, kc = (cid & 15) << 3;
            u16x8 v = *(const u16x8*)(Wxpt + (size_t)(n0 + nn) * 128 + kc);
            u32 byte = ((u32)(nn << 8) + (u32)(kc << 1)) ^ ((u32)(nn & 7) << 4);
            *(u16x8*)((char*)Bt + byte) = v;
        }
        __syncthreads();
        const int b = pr * 16 + l15;                // batch row
        const int pkg = n0 + (w << 4) + (l4 << 2);  // lane's 4 pk
        const f32x4 bias4 = *(const f32x4*)(biasp + pkg);
        const float* xr = x + (size_t)b * 1024 * 128;
        const int nnA = (w << 4) + l15;
        bool gaveup = false;

        for (int s = 0; s < nseg; ++s){
            if (s >= 3 && tid == 0 && !gaveup){     // ring-reuse throttle (depth 3)
                u64 wd = __builtin_amdgcn_s_memrealtime();
                while (AL(recdone) < 16u * (u32)(s - 2)){
                    if (__builtin_amdgcn_s_memrealtime() - wd > 1000000ull){
                        gaveup = true; break;
                    }
                    __builtin_amdgcn_s_sleep(16);
                }
            }
            __syncthreads();                        // uniform proceed

            for (int tl = 0; tl < seg; ++tl){
                int t = s * seg + tl;
                f32x4 acc = {0.f, 0.f, 0.f, 0.f};
                #pragma unroll
                for (int kf = 0; kf < 4; ++kf){
                    int k0 = kf * 32 + l4 * 8;
                    f32x4 xa = *(const f32x4*)(xr + (size_t)t * 128 + k0);
                    f32x4 xb = *(const f32x4*)(xr + (size_t)t * 128 + k0 + 4);
                    u16x8 bu;
                    bu[0]=f2bf(xa[0]); bu[1]=f2bf(xa[1]); bu[2]=f2bf(xa[2]); bu[3]=f2bf(xa[3]);
                    bu[4]=f2bf(xb[0]); bu[5]=f2bf(xb[1]); bu[6]=f2bf(xb[2]); bu[7]=f2bf(xb[3]);
                    u32 byte = ((u32)(nnA << 8) + (u32)(k0 << 1)) ^ ((u32)(nnA & 7) << 4);
                    bf16x8 af = __builtin_bit_cast(bf16x8,
                                    *(const u16x8*)((const char*)Bt + byte));
                    acc = __builtin_amdgcn_mfma_f32_16x16x32_bf16(
                              af, __builtin_bit_cast(bf16x8, bu), acc, 0, 0, 0);
                }
                acc += bias4;                       // fold bias into xg
                u16x4 o;
                o[0]=f2bf(acc[0]); o[1]=f2bf(acc[1]); o[2]=f2bf(acc[2]); o[3]=f2bf(acc[3]);
                size_t ridx = ((size_t)((s % 3) * seg + tl)) * 262144
                            + (size_t)b * 1024 + pkg;
                AS((u64*)(ring + ridx), __builtin_bit_cast(u64, o));
            }
            __syncthreads();                        // vmcnt(0): stores at IC
            if (tid == 0) AA(segcnt + s, 1u);       // publish segment
        }
    }
}

// ---------------------------------------------------------------------------
// Kernel 2: p = hT @ Wph + bph; softmax over 10.
// ---------------------------------------------------------------------------
__global__ __launch_bounds__(256) void lstm_head(
    const float* __restrict__ hT, const float* __restrict__ Wph,
    const float* __restrict__ bph, float* __restrict__ out)
{
    int b = threadIdx.x;
    float p[10];
    #pragma unroll
    for (int j = 0; j < 10; ++j) p[j] = bph[j];
    const float* hr = hT + (size_t)b * 256;
    for (int k = 0; k < 256; ++k){
        float h = hr[k];
        const float* wr = Wph + k * 10;
        #pragma unroll
        for (int j = 0; j < 10; ++j) p[j] += h * wr[j];
    }
    float m = p[0];
    #pragma unroll
    for (int j = 1; j < 10; ++j) m = fmaxf(m, p[j]);
    float s = 0.f;
    #pragma unroll
    for (int j = 0; j < 10; ++j){ p[j] = __expf(p[j] - m); s += p[j]; }
    float inv = 1.f / s;
    #pragma unroll
    for (int j = 0; j < 10; ++j) out[b * 10 + j] = p[j] * inv;
}

// ---------------------------------------------------------------------------
extern "C" void kernel_launch(void* const* d_in, const int* in_sizes, int n_in,
                              void* d_out, int out_size, void* d_ws, size_t ws_size,
                              hipStream_t stream)
{
    const float* x   = (const float*)d_in[0];
    const float* Wgx = (const float*)d_in[1];  const float* bgx = (const float*)d_in[2];
    const float* Wgh = (const float*)d_in[3];  const float* bgh = (const float*)d_in[4];
    const float* Wix = (const float*)d_in[5];  const float* bix = (const float*)d_in[6];
    const float* Wih = (const float*)d_in[7];  const float* bih = (const float*)d_in[8];
    const float* Wfx = (const float*)d_in[9];  const float* bfx = (const float*)d_in[10];
    const float* Wfh = (const float*)d_in[11]; const float* bfh = (const float*)d_in[12];
    const float* Wox = (const float*)d_in[13]; const float* box = (const float*)d_in[14];
    const float* Woh = (const float*)d_in[15]; const float* boh = (const float*)d_in[16];
    const float* Wph = (const float*)d_in[17]; const float* bph = (const float*)d_in[18];
    float* out = (float*)d_out;

    char* ws = (char*)d_ws;
    u32*   flags = (u32*)  (ws + 0);         // segcnt[1024] + recdone @1032
    float* hT    = (float*)(ws + 8192);      // 256KB -> 270336
    u16*   Whpt  = (u16*)  (ws + 270336);    // 512KB -> 794624
    u16*   Wxpt  = (u16*)  (ws + 794624);    // 256KB -> 1056768
    float* biasp = (float*)(ws + 1056768);   // 4KB   -> 1060864
    u16*   ring  = (u16*)  (ws + 1060864);   // 3 x seg x 512KB

    size_t avail = ws_size > 1060864 ? ws_size - 1060864 : 0;
    int seg = 8;
    while (seg > 1 && (size_t)3 * seg * 524288 > avail) seg >>= 1;
    int nseg = 1024 / seg;

    lstm_pack<<<dim3(512), dim3(256), 0, stream>>>(
        Wgx, Wix, Wfx, Wox, Wgh, Wih, Wfh, Woh,
        bgx, bgh, bix, bih, bfx, bfh, box, boh,
        Wxpt, Whpt, biasp, flags);
    lstm_fused<<<dim3(144), dim3(512), 0, stream>>>(
        x, Wxpt, Whpt, biasp, ring, flags, flags + 1032, hT, seg, nseg);
    lstm_head<<<dim3(1), dim3(256), 0, stream>>>(hT, Wph, bph, out);
}